// Round 2
// baseline (132.780 us; speedup 1.0000x reference)
//
#include <hip/hip_runtime.h>
#include <cmath>

// CriticSNN forward: BATCH=65536, STATE_DIM=6, HIDDEN=128, NUM_STEPS=8, OUT=1
// One wave per batch element pair; lane l owns neurons l and l+64 of each.
// Spikes are binary -> wave ballots; matmuls become masked column sums.
// R2: merged float4 weight table (rec1+fc2 share the spk1 mask walk) and
// 2-element interleave per wave to overlap the per-step latency chains.

constexpr int BATCH = 65536;
constexpr int HID   = 128;
constexpr int SDIM  = 6;
constexpr int NSTEP = 8;
constexpr int BLOCK = 1024;                         // 16 waves/block
constexpr int GRID  = 256;                          // 1 block per CU
constexpr int WAVES_TOTAL = GRID * (BLOCK / 64);    // 4096
constexpr int ELEMS_PER_WAVE = BATCH / WAVES_TOTAL; // 16 (8 pairs)

__global__ __launch_bounds__(BLOCK) void snn_fwd(
    const float* __restrict__ state,
    const float* __restrict__ w_fc1,
    const float* __restrict__ w_rec1,
    const float* __restrict__ w_fc2,
    const float* __restrict__ w_rec2,
    const float* __restrict__ w_mean,
    const float* __restrict__ w_std,
    const float* __restrict__ p_alpha1, const float* __restrict__ p_beta1,
    const float* __restrict__ p_thr1,
    const float* __restrict__ p_alpha2, const float* __restrict__ p_beta2,
    const float* __restrict__ p_thr2,
    float* __restrict__ out)
{
    // Combined table: entry(j,l) = {rec1[l][j], rec1[l+64][j], fc2[l][j], fc2[l+64][j]}
    // at index (j<<6) | (l ^ (j&63)).  XOR swizzle: distinct addresses per wave
    // read, coalesced global reads on staging.
    __shared__ float4 ld_w [HID * 64];     // 128 KiB
    __shared__ float2 ld_fc1[SDIM * 64];   // 3 KiB
    __shared__ float  ld_wm[HID];
    __shared__ float  ld_wsd[HID];

    const int tid = threadIdx.x;

    for (int v = tid; v < HID * 64; v += BLOCK) {
        const int l = v >> 7;        // 0..63
        const int j = v & 127;       // consecutive lanes -> consecutive j (coalesced)
        const int pos = (j << 6) | (l ^ (j & 63));
        ld_w[pos] = make_float4(w_rec1[l * HID + j], w_rec1[(l + 64) * HID + j],
                                w_fc2 [l * HID + j], w_fc2 [(l + 64) * HID + j]);
    }
    for (int v = tid; v < SDIM * 64; v += BLOCK) {
        const int k = v >> 6, l = v & 63;
        ld_fc1[(k << 6) | l] = make_float2(w_fc1[l * SDIM + k], w_fc1[(l + 64) * SDIM + k]);
    }
    if (tid < HID)               ld_wm [tid]       = w_mean[tid];
    else if (tid < 2 * HID)      ld_wsd[tid - HID] = w_std [tid - HID];

    const float a1 = fminf(fmaxf(p_alpha1[0], 0.f), 1.f);
    const float b1 = fminf(fmaxf(p_beta1 [0], 0.f), 1.f);
    const float a2 = fminf(fmaxf(p_alpha2[0], 0.f), 1.f);
    const float b2 = fminf(fmaxf(p_beta2 [0], 0.f), 1.f);
    const float t1 = p_thr1[0];
    const float t2 = p_thr2[0];

    __syncthreads();

    const int lane  = tid & 63;
    const int gwave = blockIdx.x * (BLOCK / 64) + (tid >> 6);

    for (int e = 0; e < ELEMS_PER_WAVE / 2; ++e) {
        int bidx[2];
        bidx[0] = gwave + WAVES_TOTAL * (2 * e);
        bidx[1] = gwave + WAVES_TOTAL * (2 * e + 1);

        float cur_a[2], cur_b[2];
        float s1a[2] = {0.f, 0.f}, s1b[2] = {0.f, 0.f};
        float m1a[2] = {0.f, 0.f}, m1b[2] = {0.f, 0.f};
        float s2a[2] = {0.f, 0.f}, s2b[2] = {0.f, 0.f};
        float m2a[2] = {0.f, 0.f}, m2b[2] = {0.f, 0.f};
        float ra [2] = {0.f, 0.f}, rb [2] = {0.f, 0.f};   // rec1 contrib for NEXT step
        float cna[2] = {0.f, 0.f}, cnb[2] = {0.f, 0.f};
        bool sp1a[2] = {false, false}, sp1b[2] = {false, false};
        bool sp2a[2] = {false, false}, sp2b[2] = {false, false};
        unsigned long long M2a[2] = {0ull, 0ull}, M2b[2] = {0ull, 0ull};

        #pragma unroll
        for (int p = 0; p < 2; ++p) {
            float ca = 0.f, cb = 0.f;
            #pragma unroll
            for (int k = 0; k < SDIM; ++k) {
                const float s = state[bidx[p] * SDIM + k];   // wave-broadcast
                const float2 w = ld_fc1[(k << 6) | lane];
                ca = fmaf(s, w.x, ca);
                cb = fmaf(s, w.y, cb);
            }
            cur_a[p] = ca; cur_b[p] = cb;
        }

        #pragma unroll 1
        for (int t = 0; t < NSTEP; ++t) {
            // ----- layer 1 state update (uses r from previous step's mask walk) -----
            unsigned long long u0, v0, u1, v1;
            #pragma unroll
            for (int p = 0; p < 2; ++p) {
                s1a[p] = fmaf(a1, s1a[p], cur_a[p] + ra[p]);
                s1b[p] = fmaf(a1, s1b[p], cur_b[p] + rb[p]);
                m1a[p] = fmaf(b1, m1a[p], s1a[p]) - (sp1a[p] ? t1 : 0.f);
                m1b[p] = fmaf(b1, m1b[p], s1b[p]) - (sp1b[p] ? t1 : 0.f);
                sp1a[p] = (m1a[p] - t1) > 0.f;
                sp1b[p] = (m1b[p] - t1) > 0.f;
                ra[p] = 0.f; rb[p] = 0.f;
            }
            u0 = __ballot(sp1a[0]); v0 = __ballot(sp1b[0]);
            u1 = __ballot(sp1a[1]); v1 = __ballot(sp1b[1]);

            // ----- fused mask walk: fc2 (this step) + rec1 (next step) -----
            float fa[2] = {0.f, 0.f}, fb[2] = {0.f, 0.f};
            while (u0 | v0 | u1 | v1) {
                if (u0) {
                    const int j = __builtin_ctzll(u0); u0 &= u0 - 1;
                    const float4 w = ld_w[(j << 6) | (lane ^ j)];
                    ra[0] += w.x; rb[0] += w.y; fa[0] += w.z; fb[0] += w.w;
                }
                if (v0) {
                    const int j0 = __builtin_ctzll(v0); v0 &= v0 - 1;
                    const float4 w = ld_w[((j0 + 64) << 6) | (lane ^ j0)];
                    ra[0] += w.x; rb[0] += w.y; fa[0] += w.z; fb[0] += w.w;
                }
                if (u1) {
                    const int j = __builtin_ctzll(u1); u1 &= u1 - 1;
                    const float4 w = ld_w[(j << 6) | (lane ^ j)];
                    ra[1] += w.x; rb[1] += w.y; fa[1] += w.z; fb[1] += w.w;
                }
                if (v1) {
                    const int j0 = __builtin_ctzll(v1); v1 &= v1 - 1;
                    const float4 w = ld_w[((j0 + 64) << 6) | (lane ^ j0)];
                    ra[1] += w.x; rb[1] += w.y; fa[1] += w.z; fb[1] += w.w;
                }
            }

            // ----- rec2 from PREVIOUS spk2 (extremely rare): global reads -----
            #pragma unroll
            for (int p = 0; p < 2; ++p) {
                unsigned long long m = M2a[p];
                while (m) {
                    const int j = __builtin_ctzll(m); m &= m - 1;
                    fa[p] += w_rec2[lane * HID + j];
                    fb[p] += w_rec2[(lane + 64) * HID + j];
                }
                m = M2b[p];
                while (m) {
                    const int j = __builtin_ctzll(m) + 64; m &= m - 1;
                    fa[p] += w_rec2[lane * HID + j];
                    fb[p] += w_rec2[(lane + 64) * HID + j];
                }
            }

            // ----- layer 2 state update -----
            #pragma unroll
            for (int p = 0; p < 2; ++p) {
                s2a[p] = fmaf(a2, s2a[p], fa[p]);
                s2b[p] = fmaf(a2, s2b[p], fb[p]);
                m2a[p] = fmaf(b2, m2a[p], s2a[p]) - (sp2a[p] ? t2 : 0.f);
                m2b[p] = fmaf(b2, m2b[p], s2b[p]) - (sp2b[p] ? t2 : 0.f);
                sp2a[p] = (m2a[p] - t2) > 0.f;
                sp2b[p] = (m2b[p] - t2) > 0.f;
                cna[p] += sp2a[p] ? 1.f : 0.f;
                cnb[p] += sp2b[p] ? 1.f : 0.f;
            }
            M2a[0] = __ballot(sp2a[0]); M2b[0] = __ballot(sp2b[0]);
            M2a[1] = __ballot(sp2a[1]); M2b[1] = __ballot(sp2b[1]);
        }

        // ----- heads -----
        float dm[2], ds[2];
        #pragma unroll
        for (int p = 0; p < 2; ++p) {
            const float avg_a = cna[p] * (1.f / (float)NSTEP);
            const float avg_b = cnb[p] * (1.f / (float)NSTEP);
            dm[p] = avg_a * ld_wm [lane] + avg_b * ld_wm [lane + 64];
            ds[p] = avg_a * ld_wsd[lane] + avg_b * ld_wsd[lane + 64];
        }
        #pragma unroll
        for (int off = 32; off > 0; off >>= 1) {
            dm[0] += __shfl_xor(dm[0], off, 64);
            ds[0] += __shfl_xor(ds[0], off, 64);
            dm[1] += __shfl_xor(dm[1], off, 64);
            ds[1] += __shfl_xor(ds[1], off, 64);
        }
        if (lane == 0) {
            #pragma unroll
            for (int p = 0; p < 2; ++p) {
                out[bidx[p]] = tanhf(dm[p]);
                const float sg = 1.f / (1.f + expf(-(ds[p] + 2.f)));
                out[BATCH + bidx[p]] = 1.9f * sg + 0.1f;
            }
        }
    }
}

extern "C" void kernel_launch(void* const* d_in, const int* in_sizes, int n_in,
                              void* d_out, int out_size, void* d_ws, size_t ws_size,
                              hipStream_t stream) {
    (void)in_sizes; (void)n_in; (void)d_ws; (void)ws_size; (void)out_size;
    snn_fwd<<<GRID, BLOCK, 0, stream>>>(
        (const float*)d_in[0],  // state
        (const float*)d_in[1],  // w_fc1
        (const float*)d_in[2],  // w_rec1
        (const float*)d_in[3],  // w_fc2
        (const float*)d_in[4],  // w_rec2
        (const float*)d_in[5],  // w_mean
        (const float*)d_in[6],  // w_std
        (const float*)d_in[7],  // alpha1
        (const float*)d_in[8],  // beta1
        (const float*)d_in[9],  // thr1
        (const float*)d_in[10], // alpha2
        (const float*)d_in[11], // beta2
        (const float*)d_in[12], // thr2
        (float*)d_out);
}